// Round 11
// baseline (349.242 us; speedup 1.0000x reference)
//
#include <hip/hip_runtime.h>
#include <hip/hip_bf16.h>

// ---------------------------------------------------------------------------
// MoE dense all-expert forward, MI355X / gfx950.  B=16384, D=H=O=256, E=32.
// Round 15: demand removal (x-in-registers), not more ILP/TLP.
//  R12-R14 post-mortem: per-CU per-k-step demands MFMA 258 / LDS 285 /
//  L1-path 256 cyc; measured 960 = serial sum. ILP and TLP grafts all flat.
//  Fix = cut LDS demand: x is EXPERT-INVARIANT, so crew0 holds x rows 0-31
//  as 16 bf16x8 register frags (loaded once) + a self-priming 4-deep ring
//  for rows 32-63 (x phase-invariant -> &31 wraparound refills are exactly
//  next phase's frags; no per-phase prologue). Crew0 LDS: 4 b128/CU-step.
//  A-rings depth 4 (~500 cyc cover >= L2 latency; regs now allow).
//  setprio REMOVED (m190: hurts lockstep crews by starving the co-wave's
//  loads).  Separate per-crew loops, same 33-barrier count each.
//  Unchanged: crew0 GEMM1(e) -> h_s dbuf, crew1 GEMM2(e-1) from h_s,
//  weights fetched once per block, lgkm-only drain barriers,
//  waves_per_eu(2,2) for the 256-reg budget (512 thr, 2 waves/SIMD).
// ---------------------------------------------------------------------------

typedef __attribute__((ext_vector_type(8))) short bf16x8;   // 8 bf16 = 4 VGPRs
typedef __attribute__((ext_vector_type(4))) float f32x4;
typedef __attribute__((ext_vector_type(16))) float f32x16;  // 32x32 C frag

__device__ __forceinline__ unsigned short f2bf(float f) {
    unsigned u = __builtin_bit_cast(unsigned, f);
    u += 0x7FFFu + ((u >> 16) & 1u);        // round-to-nearest-even
    return (unsigned short)(u >> 16);
}
__device__ __forceinline__ unsigned pack_bf16x2(float a, float b) {
    return (unsigned)f2bf(a) | ((unsigned)f2bf(b) << 16);
}

// 16B-chunk XOR swizzle for [64 rows][256 elem] bf16 tiles (index in ushorts)
#define LX(r, ch) (((r) << 8) + ((((ch) ^ ((r) & 7))) << 3))

// ------------------- W f32 -> bf16 convert + tile reorder ------------------
// Stream s = m*8 + cg: m=0 -> W1 rows cg*32..+31, m=1 -> W2 rows cg*32..+31.
// Per stream: 33 experts (e=32 is prefetch-overrun pad) x 16 k-step chunks.
// Chunk = 512 bf16 = 1 KB, element (lane, j): row = cg*32 + (lane&31),
// k = ks*16 + (lane>>5)*8 + j  — the mfma_32x32x16 A-frag order.
__global__ __launch_bounds__(256) void cvt_w(const float* __restrict__ W1,
                                             const float* __restrict__ W2,
                                             unsigned short* __restrict__ Wr) {
    int T = blockIdx.x * 256 + threadIdx.x;          // 524288 threads
    int lane = T & 63, ks = (T >> 6) & 15, e = (T >> 10) & 31;
    int cg = (T >> 15) & 7, m = (T >> 18) & 1;
    int l31 = lane & 31, hi = lane >> 5;
    const float* src = (m ? W2 : W1) +
                       ((long)e * 256 + cg * 32 + l31) * 256 + ks * 16 + hi * 8;
    float4 v0 = ((const float4*)src)[0], v1 = ((const float4*)src)[1];
    uint4 o;
    o.x = pack_bf16x2(v0.x, v0.y); o.y = pack_bf16x2(v0.z, v0.w);
    o.z = pack_bf16x2(v1.x, v1.y); o.w = pack_bf16x2(v1.z, v1.w);
    long U = (((long)(m * 8 + cg) * 33 + e) * 16 + ks) * 64 + lane;
    ((uint4*)Wr)[U] = o;
}

#define MFMA32(A, B, C) __builtin_amdgcn_mfma_f32_32x32x16_bf16(A, B, C, 0, 0, 0)

// crew0 k-step (ks literal 0..15): A-ring slot ks&3 (loaded 4 steps ago),
// refill from bumped ptrs; B rows 0-31 from xb0 regs, rows 32-63 from the
// self-priming cx1 ring (wraparound refill = next phase's frag). 4 MFMAs.
#define C0STEP(ks) do {                                                        \
    bf16x8 a0 = r0a[(ks) & 3], a1 = r0b[(ks) & 3];                             \
    r0a[(ks) & 3] = *(const bf16x8*)(p0a + ((ks) & 3) * 512);                  \
    r0b[(ks) & 3] = *(const bf16x8*)(p0b + ((ks) & 3) * 512);                  \
    bf16x8 b1 = cx1[(ks) & 3];                                                 \
    cx1[(ks) & 3] = *(const bf16x8*)                                           \
        (&x_s[LX(32 + l31, ((2 * ((ks) + 4)) & 31) + hi)]);                    \
    acc00 = MFMA32(a0, xb0[(ks)], acc00);                                      \
    acc01 = MFMA32(a0, b1, acc01);                                             \
    acc10 = MFMA32(a1, xb0[(ks)], acc10);                                      \
    acc11 = MFMA32(a1, b1, acc11);                                             \
    if (((ks) & 3) == 3) { p0a += 2048; p0b += 2048; }                         \
} while (0)

// crew1 k-step: A-ring as above; B (h) 4-deep ring from hbr, per-phase
// prologue (h changes per expert; tail refills clamped &31, garbage unused).
#define C1STEP(ks) do {                                                        \
    bf16x8 a0 = r1a[(ks) & 3], a1 = r1b[(ks) & 3];                             \
    r1a[(ks) & 3] = *(const bf16x8*)(p1a + ((ks) & 3) * 512);                  \
    r1b[(ks) & 3] = *(const bf16x8*)(p1b + ((ks) & 3) * 512);                  \
    bf16x8 b0 = cba[(ks) & 3], b1 = cbb[(ks) & 3];                             \
    cba[(ks) & 3] = *(const bf16x8*)                                           \
        (&hbr[LX(l31,      ((2 * ((ks) + 4)) & 31) + hi)]);                    \
    cbb[(ks) & 3] = *(const bf16x8*)                                           \
        (&hbr[LX(32 + l31, ((2 * ((ks) + 4)) & 31) + hi)]);                    \
    acc00 = MFMA32(a0, b0, acc00);                                             \
    acc01 = MFMA32(a0, b1, acc01);                                             \
    acc10 = MFMA32(a1, b0, acc10);                                             \
    acc11 = MFMA32(a1, b1, acc11);                                             \
    if (((ks) & 3) == 3) { p1a += 2048; p1b += 2048; }                         \
} while (0)

// Epilogue for one (cg, rg) quadrant: +b1, relu, *gate, pack -> h_s[e&1]
#define EPI(ACC, CG, RG) do {                                                  \
    const int rr = (RG) * 32 + l31;                                            \
    const float gw = gws[rr * 33 + e];                                         \
    const int rbase = rr << 8, rsw = rr & 7;                                   \
    _Pragma("unroll")                                                          \
    for (int q = 0; q < 4; ++q) {                                              \
        float4 bv = *(const float4*)(bias1 + e * 256 +                         \
                                     (2 * g + (CG)) * 32 + q * 8 + hi * 4);    \
        float v0 = fmaxf(ACC[4 * q + 0] + bv.x, 0.f) * gw;                     \
        float v1 = fmaxf(ACC[4 * q + 1] + bv.y, 0.f) * gw;                     \
        float v2 = fmaxf(ACC[4 * q + 2] + bv.z, 0.f) * gw;                     \
        float v3 = fmaxf(ACC[4 * q + 3] + bv.w, 0.f) * gw;                     \
        uint2 pk;                                                              \
        pk.x = pack_bf16x2(v0, v1);                                            \
        pk.y = pack_bf16x2(v2, v3);                                            \
        int ch = (2 * g + (CG)) * 4 + q;                                       \
        *(uint2*)(&hw[rbase + ((ch ^ rsw) << 3) + hi * 4]) = pk;               \
    }                                                                          \
} while (0)

__global__ __launch_bounds__(512)
__attribute__((amdgpu_waves_per_eu(2, 2)))
void moe_kernel(
    const float* __restrict__ x,
    const unsigned short* __restrict__ Wr,
    const float* __restrict__ bias1,
    const float* __restrict__ b2,
    const float* __restrict__ Wg,
    const float* __restrict__ bg,
    float* __restrict__ out)
{
    __shared__ __align__(16) unsigned short x_s[64 * 256];      // 32 KB
    __shared__ __align__(16) unsigned short h_s[2][64 * 256];   // 64 KB dbuf
    __shared__ float gws[64 * 33];                              // gate weights

    const int tid  = threadIdx.x;
    const int wv   = tid >> 6, lane = tid & 63;
    const int l31  = lane & 31, hi = lane >> 5;
    const int crew = wv >> 2;                   // 0 = GEMM1, 1 = GEMM2
    const int g    = wv & 3;                    // cols g*64 .. g*64+63
    const int row0 = blockIdx.x * 64;

    // ---- stage x tile: f32 global -> bf16 LDS (swizzled) ----
#pragma unroll
    for (int c = 0; c < 4; ++c) {
        int chunk = tid + c * 512;              // 2048 chunks of 8 elems
        int r = chunk >> 5, ch = chunk & 31;
        const float4* s = (const float4*)(x + (long)(row0 + r) * 256 + ch * 8);
        float4 v0 = s[0], v1 = s[1];
        uint4 o;
        o.x = pack_bf16x2(v0.x, v0.y); o.y = pack_bf16x2(v0.z, v0.w);
        o.z = pack_bf16x2(v1.x, v1.y); o.w = pack_bf16x2(v1.z, v1.w);
        *(uint4*)(&x_s[LX(r, ch)]) = o;
    }

    // ---- inline gating: 8 rows per wave, all f32 (matches reference) ----
    {
        const int e32 = lane & 31, half = lane >> 5;
        const float4* wg4 = (const float4*)(Wg + e32 * 256 + half * 128);
        float bgv = bg[e32];
        for (int i = 0; i < 8; ++i) {
            int lr = wv * 8 + i;
            const float4* xr4 = (const float4*)(x + (long)(row0 + lr) * 256 + half * 128);
            float acc = 0.f;
#pragma unroll
            for (int tt = 0; tt < 32; ++tt) {
                float4 w = wg4[tt], xv = xr4[tt];
                acc = fmaf(w.x, xv.x, acc); acc = fmaf(w.y, xv.y, acc);
                acc = fmaf(w.z, xv.z, acc); acc = fmaf(w.w, xv.w, acc);
            }
            acc += __shfl_xor(acc, 32);
            float score = (acc + bgv) / 2.71828182845904523f;   // TEMP = e

            float m = score;
#pragma unroll
            for (int d = 16; d >= 1; d >>= 1) m = fmaxf(m, __shfl_xor(m, d));
            float p_ = expf(score - m);
            float ps = p_;
#pragma unroll
            for (int d = 16; d >= 1; d >>= 1) ps += __shfl_xor(ps, d);
            float prob = p_ / ps;

            int rank = 0;
#pragma unroll
            for (int j = 0; j < 32; ++j) {
                float pj = __shfl(prob, j);
                rank += (pj > prob || (pj == prob && j < e32)) ? 1 : 0;
            }
            float kept = (rank < 22) ? prob : 0.f;
            float wsum = kept;
#pragma unroll
            for (int d = 16; d >= 1; d >>= 1) wsum += __shfl_xor(wsum, d);
            float weight = kept / (wsum + 1e-8f);

            if (half == 0) gws[lr * 33 + e32] = weight;
        }
    }

    __syncthreads();   // x_s + gws ready

    if (crew == 0) {
        // ---- x rows 0-31 in registers (expert-invariant, loaded once) ----
        bf16x8 xb0[16];
#pragma unroll
        for (int t = 0; t < 16; ++t)
            xb0[t] = *(const bf16x8*)(&x_s[LX(l31, 2 * t + hi)]);
        // rows 32-63: self-priming 4-deep ring (wraps to next phase's frags)
        bf16x8 cx1[4];
#pragma unroll
        for (int t = 0; t < 4; ++t)
            cx1[t] = *(const bf16x8*)(&x_s[LX(32 + l31, 2 * t + hi)]);

        // W1 streams (cols 2g, 2g+1), depth-4 A-rings, flow across experts
        const unsigned short* wa = Wr + (long)(2 * g) * (33 * 16 * 512) + lane * 8;
        const unsigned short* wb = Wr + (long)(2 * g + 1) * (33 * 16 * 512) + lane * 8;
        bf16x8 r0a[4], r0b[4];
#pragma unroll
        for (int t = 0; t < 4; ++t) {
            r0a[t] = *(const bf16x8*)(wa + t * 512);
            r0b[t] = *(const bf16x8*)(wb + t * 512);
        }
        const unsigned short* p0a = wa + 4 * 512;
        const unsigned short* p0b = wb + 4 * 512;

        f32x16 acc00, acc01, acc10, acc11;
#pragma unroll 1
        for (int e = 0; e < 32; ++e) {
#pragma unroll
            for (int i = 0; i < 16; ++i) {
                acc00[i] = 0.f; acc01[i] = 0.f; acc10[i] = 0.f; acc11[i] = 0.f;
            }
            C0STEP(0);  C0STEP(1);  C0STEP(2);  C0STEP(3);
            C0STEP(4);  C0STEP(5);  C0STEP(6);  C0STEP(7);
            C0STEP(8);  C0STEP(9);  C0STEP(10); C0STEP(11);
            C0STEP(12); C0STEP(13); C0STEP(14); C0STEP(15);
            // epilogue: +b1, relu, *gate -> h_s[e&1]
            unsigned short* hw = h_s[e & 1];
            EPI(acc00, 0, 0);
            EPI(acc01, 0, 1);
            EPI(acc10, 1, 0);
            EPI(acc11, 1, 1);
            asm volatile("s_waitcnt lgkmcnt(0)" ::: "memory");
            __builtin_amdgcn_s_barrier();
        }
        __builtin_amdgcn_s_barrier();   // join crew1's final phase
    } else {
        // W2 streams (cols 2g, 2g+1), depth-4 A-rings
        const unsigned short* wc = Wr + (long)(8 + 2 * g) * (33 * 16 * 512) + lane * 8;
        const unsigned short* wd = Wr + (long)(9 + 2 * g) * (33 * 16 * 512) + lane * 8;
        bf16x8 r1a[4], r1b[4];
#pragma unroll
        for (int t = 0; t < 4; ++t) {
            r1a[t] = *(const bf16x8*)(wc + t * 512);
            r1b[t] = *(const bf16x8*)(wd + t * 512);
        }
        const unsigned short* p1a = wc + 4 * 512;
        const unsigned short* p1b = wd + 4 * 512;

        // oacc init = sum_e gw * b2 (in-register bias2 combine)
        f32x16 acc00, acc01, acc10, acc11;
#pragma unroll
        for (int i = 0; i < 16; ++i) {
            acc00[i] = 0.f; acc01[i] = 0.f; acc10[i] = 0.f; acc11[i] = 0.f;
        }
        for (int ee = 0; ee < 32; ++ee) {
            float gv0 = gws[l31 * 33 + ee];
            float gv1 = gws[(32 + l31) * 33 + ee];
#pragma unroll
            for (int q = 0; q < 4; ++q) {
                float4 b0 = *(const float4*)(b2 + ee * 256 + (2 * g) * 32 + q * 8 + hi * 4);
                float4 b1 = *(const float4*)(b2 + ee * 256 + (2 * g + 1) * 32 + q * 8 + hi * 4);
                acc00[4 * q + 0] = fmaf(gv0, b0.x, acc00[4 * q + 0]);
                acc00[4 * q + 1] = fmaf(gv0, b0.y, acc00[4 * q + 1]);
                acc00[4 * q + 2] = fmaf(gv0, b0.z, acc00[4 * q + 2]);
                acc00[4 * q + 3] = fmaf(gv0, b0.w, acc00[4 * q + 3]);
                acc01[4 * q + 0] = fmaf(gv1, b0.x, acc01[4 * q + 0]);
                acc01[4 * q + 1] = fmaf(gv1, b0.y, acc01[4 * q + 1]);
                acc01[4 * q + 2] = fmaf(gv1, b0.z, acc01[4 * q + 2]);
                acc01[4 * q + 3] = fmaf(gv1, b0.w, acc01[4 * q + 3]);
                acc10[4 * q + 0] = fmaf(gv0, b1.x, acc10[4 * q + 0]);
                acc10[4 * q + 1] = fmaf(gv0, b1.y, acc10[4 * q + 1]);
                acc10[4 * q + 2] = fmaf(gv0, b1.z, acc10[4 * q + 2]);
                acc10[4 * q + 3] = fmaf(gv0, b1.w, acc10[4 * q + 3]);
                acc11[4 * q + 0] = fmaf(gv1, b1.x, acc11[4 * q + 0]);
                acc11[4 * q + 1] = fmaf(gv1, b1.y, acc11[4 * q + 1]);
                acc11[4 * q + 2] = fmaf(gv1, b1.z, acc11[4 * q + 2]);
                acc11[4 * q + 3] = fmaf(gv1, b1.w, acc11[4 * q + 3]);
            }
        }

        __builtin_amdgcn_s_barrier();   // phase 0: crew0 computes h(0)

        bf16x8 cba[4], cbb[4];
#pragma unroll 1
        for (int me = 0; me < 32; ++me) {
            const unsigned short* hbr = h_s[me & 1];
#pragma unroll
            for (int t = 0; t < 4; ++t) {
                cba[t] = *(const bf16x8*)(&hbr[LX(l31,      2 * t + hi)]);
                cbb[t] = *(const bf16x8*)(&hbr[LX(32 + l31, 2 * t + hi)]);
            }
            C1STEP(0);  C1STEP(1);  C1STEP(2);  C1STEP(3);
            C1STEP(4);  C1STEP(5);  C1STEP(6);  C1STEP(7);
            C1STEP(8);  C1STEP(9);  C1STEP(10); C1STEP(11);
            C1STEP(12); C1STEP(13); C1STEP(14); C1STEP(15);
            asm volatile("s_waitcnt lgkmcnt(0)" ::: "memory");
            __builtin_amdgcn_s_barrier();
        }

        // ---- final store: out = acc quadrants ----
#pragma unroll
        for (int q = 0; q < 4; ++q) {
            f32x4 s00 = {acc00[4 * q + 0], acc00[4 * q + 1],
                         acc00[4 * q + 2], acc00[4 * q + 3]};
            f32x4 s01 = {acc01[4 * q + 0], acc01[4 * q + 1],
                         acc01[4 * q + 2], acc01[4 * q + 3]};
            f32x4 s10 = {acc10[4 * q + 0], acc10[4 * q + 1],
                         acc10[4 * q + 2], acc10[4 * q + 3]};
            f32x4 s11 = {acc11[4 * q + 0], acc11[4 * q + 1],
                         acc11[4 * q + 2], acc11[4 * q + 3]};
            *(f32x4*)(out + (long)(row0 + l31) * 256 +
                      (2 * g) * 32 + q * 8 + hi * 4) = s00;
            *(f32x4*)(out + (long)(row0 + 32 + l31) * 256 +
                      (2 * g) * 32 + q * 8 + hi * 4) = s01;
            *(f32x4*)(out + (long)(row0 + l31) * 256 +
                      (2 * g + 1) * 32 + q * 8 + hi * 4) = s10;
            *(f32x4*)(out + (long)(row0 + 32 + l31) * 256 +
                      (2 * g + 1) * 32 + q * 8 + hi * 4) = s11;
        }
    }
}

// ------------------------------- launch ------------------------------------
extern "C" void kernel_launch(void* const* d_in, const int* in_sizes, int n_in,
                              void* d_out, int out_size, void* d_ws, size_t ws_size,
                              hipStream_t stream) {
    (void)in_sizes; (void)n_in; (void)out_size; (void)ws_size;
    const float* x  = (const float*)d_in[0];   // [16384,256]
    const float* W1 = (const float*)d_in[1];   // [32,256,256]
    const float* b1 = (const float*)d_in[2];   // [32,256]
    const float* W2 = (const float*)d_in[3];   // [32,256,256]
    const float* b2 = (const float*)d_in[4];   // [32,256]
    const float* Wg = (const float*)d_in[5];   // [32,256]
    const float* bg = (const float*)d_in[6];   // [32]
    float* out = (float*)d_out;                // [16384,256]

    // ws: Wr = 16 streams x 33 experts x 16 KB = 8.25 MiB (expert 32 = pad)
    unsigned short* Wr = (unsigned short*)d_ws;

    cvt_w<<<2048, 256, 0, stream>>>(W1, W2, Wr);
    moe_kernel<<<256, 512, 0, stream>>>(x, Wr, b1, b2, Wg, bg, out);
}